// Round 16
// baseline (443.467 us; speedup 1.0000x reference)
//
#include <hip/hip_runtime.h>
#include <hip/hip_bf16.h>
#include <cstdint>

typedef __attribute__((ext_vector_type(8))) short bf16x8;
typedef __attribute__((ext_vector_type(4))) float f32x4;

#define MFMA16(a, b, c) __builtin_amdgcn_mfma_f32_16x16x32_bf16((a), (b), (c), 0, 0, 0)

__device__ __forceinline__ ushort f2bf(float x) {
  union { float f; uint32_t u; } c; c.f = x;
  uint32_t r = (c.u + 0x7FFFu + ((c.u >> 16) & 1u)) >> 16;
  return (ushort)r;
}

__device__ __forceinline__ void gload_lds16(const ushort* g, ushort* l) {
  __builtin_amdgcn_global_load_lds((__attribute__((address_space(1))) void*)g,
                                   (__attribute__((address_space(3))) void*)l, 16, 0, 0);
}

// ---- BK=64 staging (128B rows), swizzle ((r&7)<<4): free 2-way on read ----
template <int NW, int INSTR>
__device__ __forceinline__ void stageT(const ushort* __restrict__ tileBase, int ld,
                                       ushort* lds, int wid, int lane) {
#pragma unroll
  for (int q = 0; q < INSTR; q++) {
    int r = (wid * INSTR + q) * 8 + (lane >> 3);
    int cb = ((lane & 7) * 16) ^ ((r & 7) << 4);
    gload_lds16(tileBase + (long)r * ld + (cb >> 1), lds + (wid * INSTR + q) * 512);
  }
}

__device__ __forceinline__ bf16x8 frag_read(const ushort* lds, int r, int kb) {
  int off = r * 128 + (kb ^ ((r & 7) << 4));
  return *(const bf16x8*)((const char*)lds + off);
}

// ---- BK=32 staging (64B rows). Swizzle: 16B-slot ^= (r>>1)&3. ----
template <int INSTR>
__device__ __forceinline__ void stage32(const ushort* __restrict__ tileBase, int ld,
                                        ushort* lds, int wid, int lane) {
#pragma unroll
  for (int q = 0; q < INSTR; q++) {
    int r = (wid * INSTR + q) * 16 + (lane >> 2);
    int cb = ((lane & 3) ^ ((r >> 1) & 3)) * 16;   // swizzled source byte offset
    gload_lds16(tileBase + (long)r * ld + (cb >> 1), lds + (wid * INSTR + q) * 512);
  }
}

__device__ __forceinline__ bf16x8 frag_read32(const ushort* lds, int r, int kslot) {
  int off = r * 64 + ((kslot ^ ((r >> 1) & 3)) * 16);
  return *(const bf16x8*)((const char*)lds + off);
}

__device__ __forceinline__ bf16x8 pack8(float4 a, float4 b) {
  bf16x8 v;
  v[0] = (short)f2bf(a.x); v[1] = (short)f2bf(a.y);
  v[2] = (short)f2bf(a.z); v[3] = (short)f2bf(a.w);
  v[4] = (short)f2bf(b.x); v[5] = (short)f2bf(b.y);
  v[6] = (short)f2bf(b.z); v[7] = (short)f2bf(b.w);
  return v;
}

// ---- inline top-2 over 16 expert probs ----
__device__ __forceinline__ void top2(const float* __restrict__ p, int& i0, int& i1,
                                     float& p0, float& p1) {
  float v0 = -1e30f, v1 = -1e30f; i0 = 0; i1 = 0;
#pragma unroll
  for (int e = 0; e < 16; e++) {
    float v = p[e];
    if (v > v0) { v1 = v0; i1 = i0; v0 = v; i0 = e; }
    else if (v > v1) { v1 = v; i1 = e; }
  }
  float s = 1.0f / (v0 + v1 + 1e-8f);
  p0 = v0 * s; p1 = v1 * s;
}

// -------- f32 -> bf16: hidden only (all weights converted in-consumer) --------
__global__ void cvt_h(const float* __restrict__ hidden, ushort* __restrict__ h_bf) {
  const long n4 = 2097152L / 4;
  long stride = (long)gridDim.x * blockDim.x;
  for (long g = (long)blockIdx.x * blockDim.x + threadIdx.x; g < n4; g += stride) {
    float4 v = ((const float4*)hidden)[g];
    ((ushort4*)h_bf)[g] = make_ushort4(f2bf(v.x), f2bf(v.y), f2bf(v.z), f2bf(v.w));
  }
}

// ---- fused gate/up: 128x64 dual-B tiles, BK=32, weights converted f32->bf16 in-kernel ----
__global__ __launch_bounds__(256, 3) void gateup128(
    const ushort* __restrict__ Hb, const float* __restrict__ Wgf,
    const float* __restrict__ Wuf, const float* __restrict__ eprobs,
    ushort* __restrict__ G) {
  constexpr int Hd = 512, I = 2048, S = 512, NTT = 16;
  __shared__ ushort As[2][128 * 32], B1s[2][64 * 32], B2s[2][64 * 32];  // 32 KiB

  int wg = blockIdx.x;                       // 2048 blocks
  int swz = (wg & 7) * 256 + (wg >> 3);
  int p = swz >> 7;
  int r7 = swz & 127;
  int rowT = r7 & 3, colT = r7 >> 2;         // 4 consecutive blocks share B panels
  const int b = p >> 1;
  int i0, i1; float q0, q1;
  top2(eprobs + b * 16, i0, i1, q0, q1);
  const int eid = (p & 1) ? i1 : i0;
  const int row0 = rowT * 128, col0 = colT * 64;
  const ushort* Ab  = Hb + ((long)b * S + row0) * Hd;
  const float*  B1f = Wgf + ((long)eid * I + col0) * Hd;
  const float*  B2f = Wuf + ((long)eid * I + col0) * Hd;

  const int tid = threadIdx.x, wid = tid >> 6, lane = tid & 63;
  const int wr = wid >> 1, wc = wid & 1;     // wave: 64 rows x 32 cols
  const int l15 = lane & 15;
  const int kslot = lane >> 4;
  const int rB = tid >> 2, sB = tid & 3;     // B staging: 4 thr/row, 16B bf16 slots

  f32x4 acc1[4][2] = {};
  f32x4 acc2[4][2] = {};
  float4 b1a, b1b, b2a, b2b;                 // in-flight B regs

  auto ldB = [&](int t) {
    const float* p1 = B1f + (long)rB * Hd + t * 32 + sB * 8;
    const float* p2 = B2f + (long)rB * Hd + t * 32 + sB * 8;
    b1a = *(const float4*)p1; b1b = *(const float4*)(p1 + 4);
    b2a = *(const float4*)p2; b2b = *(const float4*)(p2 + 4);
  };
  auto wrB = [&](int buf) {
    int off = rB * 64 + ((sB ^ ((rB >> 1) & 3)) * 16);
    *(bf16x8*)((char*)B1s[buf] + off) = pack8(b1a, b1b);
    *(bf16x8*)((char*)B2s[buf] + off) = pack8(b2a, b2b);
  };

  // prologue: B(0) regs, A(0), write B(0), issue B(1)
  ldB(0);                                   // 8 vm
  stage32<2>(Ab, Hd, As[0], wid, lane);     // 2 vm
  asm volatile("s_waitcnt vmcnt(2)" ::: "memory");   // retire B(0)
  wrB(0);
  ldB(1);                                   // 8 vm
  asm volatile("s_waitcnt lgkmcnt(0)" ::: "memory");
  __builtin_amdgcn_sched_barrier(0);

  for (int t = 0; t < NTT; t++) {
    if (t + 1 < NTT) {
      stage32<2>(Ab + (t + 1) * 32, Hd, As[(t + 1) & 1], wid, lane);
      asm volatile("s_waitcnt vmcnt(10)" ::: "memory");   // retire A(t)
    } else {
      asm volatile("s_waitcnt vmcnt(0)" ::: "memory");
    }
    __builtin_amdgcn_s_barrier();
    __builtin_amdgcn_sched_barrier(0);
    const ushort* as = As[t & 1];
    bf16x8 av[4], bv[2];
#pragma unroll
    for (int i = 0; i < 4; i++) av[i] = frag_read32(as, wr * 64 + i * 16 + l15, kslot);
#pragma unroll
    for (int j = 0; j < 2; j++) bv[j] = frag_read32(B1s[t & 1], wc * 32 + j * 16 + l15, kslot);
    __builtin_amdgcn_s_setprio(1);
#pragma unroll
    for (int i = 0; i < 4; i++)
#pragma unroll
      for (int j = 0; j < 2; j++) acc1[i][j] = MFMA16(av[i], bv[j], acc1[i][j]);
    __builtin_amdgcn_s_setprio(0);
#pragma unroll
    for (int j = 0; j < 2; j++) bv[j] = frag_read32(B2s[t & 1], wc * 32 + j * 16 + l15, kslot);
    __builtin_amdgcn_s_setprio(1);
#pragma unroll
    for (int i = 0; i < 4; i++)
#pragma unroll
      for (int j = 0; j < 2; j++) acc2[i][j] = MFMA16(av[i], bv[j], acc2[i][j]);
    __builtin_amdgcn_s_setprio(0);
    if (t + 1 < NTT) {
      asm volatile("s_waitcnt vmcnt(2)" ::: "memory");    // retire B(t+1) regs
      wrB((t + 1) & 1);
      if (t + 2 < NTT) ldB(t + 2);
    }
    asm volatile("s_waitcnt lgkmcnt(0)" ::: "memory");
    __builtin_amdgcn_sched_barrier(0);
    __builtin_amdgcn_s_barrier();
  }

  ushort* Gout = G + (long)p * S * I;
#pragma unroll
  for (int i = 0; i < 4; i++) {
    int r = row0 + wr * 64 + i * 16 + ((lane >> 4) * 4);
#pragma unroll
    for (int j = 0; j < 2; j++) {
      int c = col0 + wc * 32 + j * 16 + l15;
#pragma unroll
      for (int q = 0; q < 4; q++) {
        float g = acc1[i][j][q], u = acc2[i][j][q];
        float sg = g / (1.0f + __expf(-g));
        Gout[(long)(r + q) * I + c] = f2bf(sg * u);
      }
    }
  }
}

// ---- fused down GEMM + combine, Wd converted f32->bf16 in-kernel ----
__global__ __launch_bounds__(256) void down_fused(
    const ushort* __restrict__ G, const float* __restrict__ Wdf,
    const float* __restrict__ eprobs, ushort* __restrict__ Cb) {
  constexpr int I = 2048, Hd = 512, S = 512, NT = 64;
  const int b = blockIdx.z;
  const int row0 = blockIdx.x * 128, col0 = blockIdx.y * 32;
  __shared__ ushort As[2][128 * 64], Bs[2][32 * 64];  // 40 KiB
  const int tid = threadIdx.x, wid = tid >> 6, lane = tid & 63;
  int e0, e1; float p0, p1;
  top2(eprobs + b * 16, e0, e1, p0, p1);
  const ushort* A0 = G + ((long)(2 * b) * S + row0) * I;
  const ushort* A1 = G + ((long)(2 * b + 1) * S + row0) * I;
  const int rB = tid >> 3, sB = tid & 7;     // B staging: 8 thr/row, 16B bf16 slots

  f32x4 acc[2][2] = {};
  float4 bda, bdb;

  auto stA = [&](int t2, int buf) {
    const ushort* An = (t2 < 32 ? A0 + t2 * 64 : A1 + (t2 - 32) * 64);
    stageT<4, 4>(An, I, As[buf], wid, lane);
  };
  auto ldB = [&](int t2) {
    int e = (t2 < 32) ? e0 : e1;
    const float* pb = Wdf + ((long)e * Hd + col0 + rB) * I + (t2 & 31) * 64 + sB * 8;
    bda = *(const float4*)pb; bdb = *(const float4*)(pb + 4);
  };
  auto wrB = [&](int buf) {
    int off = rB * 128 + ((sB * 16) ^ ((rB & 7) << 4));
    *(bf16x8*)((char*)Bs[buf] + off) = pack8(bda, bdb);
  };

  ldB(0);                 // 2 vm
  stA(0, 0);              // 4 vm
  asm volatile("s_waitcnt vmcnt(4)" ::: "memory");   // retire B(0)
  wrB(0);
  ldB(1);                 // 2 vm
  asm volatile("s_waitcnt lgkmcnt(0)" ::: "memory");
  __builtin_amdgcn_sched_barrier(0);

  for (int t = 0; t < NT; t++) {
    if (t + 1 < NT) {
      stA(t + 1, (t + 1) & 1);
      asm volatile("s_waitcnt vmcnt(6)" ::: "memory");   // retire A(t)
    } else {
      asm volatile("s_waitcnt vmcnt(0)" ::: "memory");
    }
    __builtin_amdgcn_s_barrier();
    __builtin_amdgcn_sched_barrier(0);
    if (t == 32) {
      float ratio = p0 / p1;
#pragma unroll
      for (int i = 0; i < 2; i++)
#pragma unroll
        for (int j = 0; j < 2; j++) acc[i][j] *= ratio;
    }
#pragma unroll
    for (int ks = 0; ks < 2; ks++) {
      const int kb = ks * 64 + ((lane >> 4) * 16);
      bf16x8 av[2], bv[2];
#pragma unroll
      for (int i = 0; i < 2; i++) av[i] = frag_read(As[t & 1], wid * 32 + i * 16 + (lane & 15), kb);
#pragma unroll
      for (int j = 0; j < 2; j++) bv[j] = frag_read(Bs[t & 1], j * 16 + (lane & 15), kb);
      __builtin_amdgcn_s_setprio(1);
#pragma unroll
      for (int i = 0; i < 2; i++)
#pragma unroll
        for (int j = 0; j < 2; j++) acc[i][j] = MFMA16(av[i], bv[j], acc[i][j]);
      __builtin_amdgcn_s_setprio(0);
    }
    if (t + 1 < NT) {
      asm volatile("s_waitcnt vmcnt(4)" ::: "memory");   // retire B(t+1) regs
      wrB((t + 1) & 1);
      if (t + 2 < NT) ldB(t + 2);
    }
    asm volatile("s_waitcnt lgkmcnt(0)" ::: "memory");
    __builtin_amdgcn_sched_barrier(0);
    __builtin_amdgcn_s_barrier();
  }

  ushort* Co = Cb + ((long)b * S + row0) * Hd + col0;
#pragma unroll
  for (int i = 0; i < 2; i++) {
    int r = wid * 32 + i * 16 + ((lane >> 4) * 4);
#pragma unroll
    for (int j = 0; j < 2; j++) {
      int c = j * 16 + (lane & 15);
#pragma unroll
      for (int q = 0; q < 4; q++)
        Co[(long)(r + q) * Hd + c] = f2bf(p1 * acc[i][j][q]);
    }
  }
}

// -------- final projection: 128x128, BK=32, 4 waves, 4 blocks/CU, NT stores --------
// B (Wout) consumed as f32, converted in-staging (gateup-proven FIFO: top vmcnt(6)
// retires A(t); tail vmcnt(2) retires B(t+1) regs). A (Cb bf16) via global_load_lds.
// NOTE: launch_bounds (256,5) spilled acc (VGPR 88->48, 700 us); 4 is the sweet spot.
// nt stores on the 524 MB terminal output: -56 us (R9->R10).
__global__ __launch_bounds__(256, 4) void gemm128_final(
    const ushort* __restrict__ A,   // [4096][512] bf16 (combined)
    const float*  __restrict__ W,   // [32000][512] f32 (Wout)
    float* __restrict__ Out) {      // [4096][32000] f32
  constexpr int K = 512, NTT = 16, LDC = 32000;
  __shared__ ushort As[2][128 * 32], Bs[2][128 * 32];  // 32 KiB

  int wg = blockIdx.x;                          // 8000 blocks, 8000 % 8 == 0
  int swz = (wg & 7) * 1000 + (wg >> 3);
  const int colT = swz / 32, rowT = swz % 32;   // 32 row-tiles share each B col-panel
  const int row0 = rowT * 128, col0 = colT * 128;

  const int tid = threadIdx.x, wid = tid >> 6, lane = tid & 63;
  const int wr = wid >> 1, wc = wid & 1;        // wave tile: 64 rows x 64 cols
  const int l15 = lane & 15;
  const int kslot = lane >> 4;
  const int rB = tid >> 1, sB = (tid & 1) * 2;  // B staging: 2 thr/row, 2 slots each

  const ushort* Ab = A + (long)row0 * K;
  const float*  Wb = W + (long)col0 * K;
  f32x4 acc[4][4] = {};
  float4 w0, w1, w2, w3;                        // in-flight B regs (16 f32)

  auto ldB = [&](int t) {
    const float* pb = Wb + (long)rB * K + t * 32 + sB * 8;
    w0 = *(const float4*)pb;      w1 = *(const float4*)(pb + 4);
    w2 = *(const float4*)(pb + 8); w3 = *(const float4*)(pb + 12);
  };
  auto wrB = [&](int buf) {
    int o0 = rB * 64 + (((sB + 0) ^ ((rB >> 1) & 3)) * 16);
    int o1 = rB * 64 + (((sB + 1) ^ ((rB >> 1) & 3)) * 16);
    *(bf16x8*)((char*)Bs[buf] + o0) = pack8(w0, w1);
    *(bf16x8*)((char*)Bs[buf] + o1) = pack8(w2, w3);
  };

  // prologue: B(0) regs, A(0), write B(0), issue B(1)
  ldB(0);                                   // 4 vm
  stage32<2>(Ab, K, As[0], wid, lane);      // 2 vm
  asm volatile("s_waitcnt vmcnt(2)" ::: "memory");   // retire B(0)
  wrB(0);
  ldB(1);                                   // 4 vm -> outstanding A(0)2 + B(1)4
  asm volatile("s_waitcnt lgkmcnt(0)" ::: "memory");
  __builtin_amdgcn_sched_barrier(0);

  for (int t = 0; t < NTT; t++) {
    if (t + 1 < NTT) {
      stage32<2>(Ab + (t + 1) * 32, K, As[(t + 1) & 1], wid, lane);
      asm volatile("s_waitcnt vmcnt(6)" ::: "memory");   // retire A(t)
    } else {
      asm volatile("s_waitcnt vmcnt(0)" ::: "memory");
    }
    __builtin_amdgcn_s_barrier();
    __builtin_amdgcn_sched_barrier(0);
    const ushort* as = As[t & 1];
    const ushort* bs = Bs[t & 1];
    bf16x8 av[4], bv[4];
#pragma unroll
    for (int i = 0; i < 4; i++) av[i] = frag_read32(as, wr * 64 + i * 16 + l15, kslot);
#pragma unroll
    for (int j = 0; j < 4; j++) bv[j] = frag_read32(bs, wc * 64 + j * 16 + l15, kslot);
    __builtin_amdgcn_s_setprio(1);
#pragma unroll
    for (int i = 0; i < 4; i++)
#pragma unroll
      for (int j = 0; j < 4; j++)
        acc[i][j] = MFMA16(av[i], bv[j], acc[i][j]);
    __builtin_amdgcn_s_setprio(0);
    if (t + 1 < NTT) {
      asm volatile("s_waitcnt vmcnt(2)" ::: "memory");   // retire B(t+1) regs
      wrB((t + 1) & 1);
      if (t + 2 < NTT) ldB(t + 2);
    }
    asm volatile("s_waitcnt lgkmcnt(0)" ::: "memory");
    __builtin_amdgcn_sched_barrier(0);
    __builtin_amdgcn_s_barrier();
  }

  // nt stores: 64B contiguous sectors, no L2 allocation (keeps A/B panels resident).
#pragma unroll
  for (int i = 0; i < 4; i++) {
    int r = row0 + wr * 64 + i * 16 + ((lane >> 4) * 4);
#pragma unroll
    for (int j = 0; j < 4; j++) {
      int c = col0 + wc * 64 + j * 16 + l15;
#pragma unroll
      for (int q = 0; q < 4; q++)
        __builtin_nontemporal_store(acc[i][j][q], &Out[(long)(r + q) * LDC + c]);
    }
  }
}

extern "C" void kernel_launch(void* const* d_in, const int* in_sizes, int n_in,
                              void* d_out, int out_size, void* d_ws, size_t ws_size,
                              hipStream_t stream) {
  const float* hidden = (const float*)d_in[0];   // [8,512,512]
  const float* eprobs = (const float*)d_in[1];   // [8,16]
  const float* Wg     = (const float*)d_in[2];   // [16,2048,512]
  const float* Wu     = (const float*)d_in[3];   // [16,2048,512]
  const float* Wd     = (const float*)d_in[4];   // [16,512,2048]
  const float* Wout   = (const float*)d_in[5];   // [32000,512]
  float* out = (float*)d_out;                    // [8,512,32000] f32

  char* ws = (char*)d_ws;
  ushort* h_bf  = (ushort*)(ws + 256);         // 8*512*512
  ushort* Gbuf  = h_bf + 2097152L;             // 16*512*2048 bf16
  ushort* Cb    = Gbuf + 16777216L;            // 8*512*512 bf16

  // hidden f32->bf16 (12 MB); all weight conversions are fused into consumers.
  hipLaunchKernelGGL(cvt_h, dim3(512), dim3(256), 0, stream, hidden, h_bf);
  // gate/up: Wg/Wu consumed as f32 (conversion fused into staging)
  hipLaunchKernelGGL(gateup128, dim3(2048), dim3(256), 0, stream,
                     h_bf, Wg, Wu, eprobs, Gbuf);
  // down + combine: Wd consumed as f32
  hipLaunchKernelGGL(down_fused, dim3(4, 16, 8), dim3(256), 0, stream,
                     Gbuf, Wd, eprobs, Cb);
  // output projection: Wout consumed as f32, 8000 blocks, 4 blocks/CU, nt stores
  hipLaunchKernelGGL(gemm128_final, dim3(8000), dim3(256), 0, stream, Cb, Wout, out);
}

// Round 17
// 326.671 us; speedup vs baseline: 1.3575x; 1.3575x over previous
//
#include <hip/hip_runtime.h>
#include <hip/hip_bf16.h>
#include <cstdint>

typedef __attribute__((ext_vector_type(8))) short bf16x8;
typedef __attribute__((ext_vector_type(4))) float f32x4;

#define MFMA16(a, b, c) __builtin_amdgcn_mfma_f32_16x16x32_bf16((a), (b), (c), 0, 0, 0)

__device__ __forceinline__ ushort f2bf(float x) {
  union { float f; uint32_t u; } c; c.f = x;
  uint32_t r = (c.u + 0x7FFFu + ((c.u >> 16) & 1u)) >> 16;
  return (ushort)r;
}

__device__ __forceinline__ void gload_lds16(const ushort* g, ushort* l) {
  __builtin_amdgcn_global_load_lds((__attribute__((address_space(1))) void*)g,
                                   (__attribute__((address_space(3))) void*)l, 16, 0, 0);
}

// ---- BK=64 staging (128B rows), swizzle ((r&7)<<4): free 2-way on read ----
template <int NW, int INSTR>
__device__ __forceinline__ void stageT(const ushort* __restrict__ tileBase, int ld,
                                       ushort* lds, int wid, int lane) {
#pragma unroll
  for (int q = 0; q < INSTR; q++) {
    int r = (wid * INSTR + q) * 8 + (lane >> 3);
    int cb = ((lane & 7) * 16) ^ ((r & 7) << 4);
    gload_lds16(tileBase + (long)r * ld + (cb >> 1), lds + (wid * INSTR + q) * 512);
  }
}

__device__ __forceinline__ bf16x8 frag_read(const ushort* lds, int r, int kb) {
  int off = r * 128 + (kb ^ ((r & 7) << 4));
  return *(const bf16x8*)((const char*)lds + off);
}

// ---- BK=32 staging (64B rows). Swizzle: 16B-slot ^= (r>>1)&3. ----
template <int INSTR>
__device__ __forceinline__ void stage32(const ushort* __restrict__ tileBase, int ld,
                                        ushort* lds, int wid, int lane) {
#pragma unroll
  for (int q = 0; q < INSTR; q++) {
    int r = (wid * INSTR + q) * 16 + (lane >> 2);
    int cb = ((lane & 3) ^ ((r >> 1) & 3)) * 16;   // swizzled source byte offset
    gload_lds16(tileBase + (long)r * ld + (cb >> 1), lds + (wid * INSTR + q) * 512);
  }
}

__device__ __forceinline__ bf16x8 frag_read32(const ushort* lds, int r, int kslot) {
  int off = r * 64 + ((kslot ^ ((r >> 1) & 3)) * 16);
  return *(const bf16x8*)((const char*)lds + off);
}

__device__ __forceinline__ bf16x8 pack8(float4 a, float4 b) {
  bf16x8 v;
  v[0] = (short)f2bf(a.x); v[1] = (short)f2bf(a.y);
  v[2] = (short)f2bf(a.z); v[3] = (short)f2bf(a.w);
  v[4] = (short)f2bf(b.x); v[5] = (short)f2bf(b.y);
  v[6] = (short)f2bf(b.z); v[7] = (short)f2bf(b.w);
  return v;
}

// ---- inline top-2 over 16 expert probs ----
__device__ __forceinline__ void top2(const float* __restrict__ p, int& i0, int& i1,
                                     float& p0, float& p1) {
  float v0 = -1e30f, v1 = -1e30f; i0 = 0; i1 = 0;
#pragma unroll
  for (int e = 0; e < 16; e++) {
    float v = p[e];
    if (v > v0) { v1 = v0; i1 = i0; v0 = v; i0 = e; }
    else if (v > v1) { v1 = v; i1 = e; }
  }
  float s = 1.0f / (v0 + v1 + 1e-8f);
  p0 = v0 * s; p1 = v1 * s;
}

// -------- f32 -> bf16: hidden + Wout (expert weights converted in-consumer) --------
// Wout stays a cvt pass: fusing it into the final spilled (R16: VGPR 88->64,
// +105 MB scratch, final 188->360 us). Fusion needs VGPR headroom the final lacks.
__global__ void cvt_hw(const float* __restrict__ hidden, const float* __restrict__ wout,
                       ushort* __restrict__ h_bf, ushort* __restrict__ wo_bf) {
  const long h4 = 2097152L / 4, w4 = 16384000L / 4, n4 = h4 + w4;
  long stride = (long)gridDim.x * blockDim.x;
  for (long g = (long)blockIdx.x * blockDim.x + threadIdx.x; g < n4; g += stride) {
    const float* src; ushort* dst; long o;
    if (g < h4) { src = hidden; dst = h_bf; o = g; }
    else { src = wout; dst = wo_bf; o = g - h4; }
    float4 v = ((const float4*)src)[o];
    ((ushort4*)dst)[o] = make_ushort4(f2bf(v.x), f2bf(v.y), f2bf(v.z), f2bf(v.w));
  }
}

// ---- fused gate/up: 128x64 dual-B tiles, BK=32, weights converted f32->bf16 in-kernel ----
// A via global_load_lds; B1/B2 reg-staged (T14 split). FIFO/iter: [A(t)2, B(t+1)8, A(t+1)2]:
// top vmcnt(10) retires A(t); mid vmcnt(2) retires B(t+1).
__global__ __launch_bounds__(256, 3) void gateup128(
    const ushort* __restrict__ Hb, const float* __restrict__ Wgf,
    const float* __restrict__ Wuf, const float* __restrict__ eprobs,
    ushort* __restrict__ G) {
  constexpr int Hd = 512, I = 2048, S = 512, NTT = 16;
  __shared__ ushort As[2][128 * 32], B1s[2][64 * 32], B2s[2][64 * 32];  // 32 KiB

  int wg = blockIdx.x;                       // 2048 blocks
  int swz = (wg & 7) * 256 + (wg >> 3);
  int p = swz >> 7;
  int r7 = swz & 127;
  int rowT = r7 & 3, colT = r7 >> 2;         // 4 consecutive blocks share B panels
  const int b = p >> 1;
  int i0, i1; float q0, q1;
  top2(eprobs + b * 16, i0, i1, q0, q1);
  const int eid = (p & 1) ? i1 : i0;
  const int row0 = rowT * 128, col0 = colT * 64;
  const ushort* Ab  = Hb + ((long)b * S + row0) * Hd;
  const float*  B1f = Wgf + ((long)eid * I + col0) * Hd;
  const float*  B2f = Wuf + ((long)eid * I + col0) * Hd;

  const int tid = threadIdx.x, wid = tid >> 6, lane = tid & 63;
  const int wr = wid >> 1, wc = wid & 1;     // wave: 64 rows x 32 cols
  const int l15 = lane & 15;
  const int kslot = lane >> 4;
  const int rB = tid >> 2, sB = tid & 3;     // B staging: 4 thr/row, 16B bf16 slots

  f32x4 acc1[4][2] = {};
  f32x4 acc2[4][2] = {};
  float4 b1a, b1b, b2a, b2b;                 // in-flight B regs

  auto ldB = [&](int t) {
    const float* p1 = B1f + (long)rB * Hd + t * 32 + sB * 8;
    const float* p2 = B2f + (long)rB * Hd + t * 32 + sB * 8;
    b1a = *(const float4*)p1; b1b = *(const float4*)(p1 + 4);
    b2a = *(const float4*)p2; b2b = *(const float4*)(p2 + 4);
  };
  auto wrB = [&](int buf) {
    int off = rB * 64 + ((sB ^ ((rB >> 1) & 3)) * 16);
    *(bf16x8*)((char*)B1s[buf] + off) = pack8(b1a, b1b);
    *(bf16x8*)((char*)B2s[buf] + off) = pack8(b2a, b2b);
  };

  // prologue: B(0) regs, A(0), write B(0), issue B(1)
  ldB(0);                                   // 8 vm
  stage32<2>(Ab, Hd, As[0], wid, lane);     // 2 vm
  asm volatile("s_waitcnt vmcnt(2)" ::: "memory");   // retire B(0)
  wrB(0);
  ldB(1);                                   // 8 vm
  asm volatile("s_waitcnt lgkmcnt(0)" ::: "memory");
  __builtin_amdgcn_sched_barrier(0);

  for (int t = 0; t < NTT; t++) {
    if (t + 1 < NTT) {
      stage32<2>(Ab + (t + 1) * 32, Hd, As[(t + 1) & 1], wid, lane);
      asm volatile("s_waitcnt vmcnt(10)" ::: "memory");   // retire A(t)
    } else {
      asm volatile("s_waitcnt vmcnt(0)" ::: "memory");
    }
    __builtin_amdgcn_s_barrier();
    __builtin_amdgcn_sched_barrier(0);
    const ushort* as = As[t & 1];
    bf16x8 av[4], bv[2];
#pragma unroll
    for (int i = 0; i < 4; i++) av[i] = frag_read32(as, wr * 64 + i * 16 + l15, kslot);
#pragma unroll
    for (int j = 0; j < 2; j++) bv[j] = frag_read32(B1s[t & 1], wc * 32 + j * 16 + l15, kslot);
    __builtin_amdgcn_s_setprio(1);
#pragma unroll
    for (int i = 0; i < 4; i++)
#pragma unroll
      for (int j = 0; j < 2; j++) acc1[i][j] = MFMA16(av[i], bv[j], acc1[i][j]);
    __builtin_amdgcn_s_setprio(0);
#pragma unroll
    for (int j = 0; j < 2; j++) bv[j] = frag_read32(B2s[t & 1], wc * 32 + j * 16 + l15, kslot);
    __builtin_amdgcn_s_setprio(1);
#pragma unroll
    for (int i = 0; i < 4; i++)
#pragma unroll
      for (int j = 0; j < 2; j++) acc2[i][j] = MFMA16(av[i], bv[j], acc2[i][j]);
    __builtin_amdgcn_s_setprio(0);
    if (t + 1 < NTT) {
      asm volatile("s_waitcnt vmcnt(2)" ::: "memory");    // retire B(t+1) regs
      wrB((t + 1) & 1);
      if (t + 2 < NTT) ldB(t + 2);
    }
    asm volatile("s_waitcnt lgkmcnt(0)" ::: "memory");
    __builtin_amdgcn_sched_barrier(0);
    __builtin_amdgcn_s_barrier();
  }

  ushort* Gout = G + (long)p * S * I;
#pragma unroll
  for (int i = 0; i < 4; i++) {
    int r = row0 + wr * 64 + i * 16 + ((lane >> 4) * 4);
#pragma unroll
    for (int j = 0; j < 2; j++) {
      int c = col0 + wc * 32 + j * 16 + l15;
#pragma unroll
      for (int q = 0; q < 4; q++) {
        float g = acc1[i][j][q], u = acc2[i][j][q];
        float sg = g / (1.0f + __expf(-g));
        Gout[(long)(r + q) * I + c] = f2bf(sg * u);
      }
    }
  }
}

// ---- fused down GEMM + combine, Wd converted f32->bf16 in-kernel ----
// FIFO/iter: [A(t)4, B(t+1)2, A(t+1)4]: top vmcnt(6) retires A(t); mid vmcnt(4) B(t+1).
__global__ __launch_bounds__(256) void down_fused(
    const ushort* __restrict__ G, const float* __restrict__ Wdf,
    const float* __restrict__ eprobs, ushort* __restrict__ Cb) {
  constexpr int I = 2048, Hd = 512, S = 512, NT = 64;
  const int b = blockIdx.z;
  const int row0 = blockIdx.x * 128, col0 = blockIdx.y * 32;
  __shared__ ushort As[2][128 * 64], Bs[2][32 * 64];  // 40 KiB
  const int tid = threadIdx.x, wid = tid >> 6, lane = tid & 63;
  int e0, e1; float p0, p1;
  top2(eprobs + b * 16, e0, e1, p0, p1);
  const ushort* A0 = G + ((long)(2 * b) * S + row0) * I;
  const ushort* A1 = G + ((long)(2 * b + 1) * S + row0) * I;
  const int rB = tid >> 3, sB = tid & 7;     // B staging: 8 thr/row, 16B bf16 slots

  f32x4 acc[2][2] = {};
  float4 bda, bdb;

  auto stA = [&](int t2, int buf) {
    const ushort* An = (t2 < 32 ? A0 + t2 * 64 : A1 + (t2 - 32) * 64);
    stageT<4, 4>(An, I, As[buf], wid, lane);
  };
  auto ldB = [&](int t2) {
    int e = (t2 < 32) ? e0 : e1;
    const float* pb = Wdf + ((long)e * Hd + col0 + rB) * I + (t2 & 31) * 64 + sB * 8;
    bda = *(const float4*)pb; bdb = *(const float4*)(pb + 4);
  };
  auto wrB = [&](int buf) {
    int off = rB * 128 + ((sB * 16) ^ ((rB & 7) << 4));
    *(bf16x8*)((char*)Bs[buf] + off) = pack8(bda, bdb);
  };

  ldB(0);                 // 2 vm
  stA(0, 0);              // 4 vm
  asm volatile("s_waitcnt vmcnt(4)" ::: "memory");   // retire B(0)
  wrB(0);
  ldB(1);                 // 2 vm
  asm volatile("s_waitcnt lgkmcnt(0)" ::: "memory");
  __builtin_amdgcn_sched_barrier(0);

  for (int t = 0; t < NT; t++) {
    if (t + 1 < NT) {
      stA(t + 1, (t + 1) & 1);
      asm volatile("s_waitcnt vmcnt(6)" ::: "memory");   // retire A(t)
    } else {
      asm volatile("s_waitcnt vmcnt(0)" ::: "memory");
    }
    __builtin_amdgcn_s_barrier();
    __builtin_amdgcn_sched_barrier(0);
    if (t == 32) {
      float ratio = p0 / p1;
#pragma unroll
      for (int i = 0; i < 2; i++)
#pragma unroll
        for (int j = 0; j < 2; j++) acc[i][j] *= ratio;
    }
#pragma unroll
    for (int ks = 0; ks < 2; ks++) {
      const int kb = ks * 64 + ((lane >> 4) * 16);
      bf16x8 av[2], bv[2];
#pragma unroll
      for (int i = 0; i < 2; i++) av[i] = frag_read(As[t & 1], wid * 32 + i * 16 + (lane & 15), kb);
#pragma unroll
      for (int j = 0; j < 2; j++) bv[j] = frag_read(Bs[t & 1], j * 16 + (lane & 15), kb);
      __builtin_amdgcn_s_setprio(1);
#pragma unroll
      for (int i = 0; i < 2; i++)
#pragma unroll
        for (int j = 0; j < 2; j++) acc[i][j] = MFMA16(av[i], bv[j], acc[i][j]);
      __builtin_amdgcn_s_setprio(0);
    }
    if (t + 1 < NT) {
      asm volatile("s_waitcnt vmcnt(4)" ::: "memory");   // retire B(t+1) regs
      wrB((t + 1) & 1);
      if (t + 2 < NT) ldB(t + 2);
    }
    asm volatile("s_waitcnt lgkmcnt(0)" ::: "memory");
    __builtin_amdgcn_sched_barrier(0);
    __builtin_amdgcn_s_barrier();
  }

  ushort* Co = Cb + ((long)b * S + row0) * Hd + col0;
#pragma unroll
  for (int i = 0; i < 2; i++) {
    int r = wid * 32 + i * 16 + ((lane >> 4) * 4);
#pragma unroll
    for (int j = 0; j < 2; j++) {
      int c = j * 16 + (lane & 15);
#pragma unroll
      for (int q = 0; q < 4; q++)
        Co[(long)(r + q) * Hd + c] = f2bf(p1 * acc[i][j][q]);
    }
  }
}

// -------- final projection: 128x128, BK=32, 4 waves, 4 blocks/CU, NT stores --------
// Both operands bf16 via global_load_lds (register-free staging). launch_bounds
// (256,5) spilled (R11); Wout f32 reg-fusion spilled (R16). 4 blocks/CU + bf16 B
// is the proven envelope. nt stores on the 524 MB terminal output: -56 us.
__global__ __launch_bounds__(256, 4) void gemm128_final(
    const ushort* __restrict__ A,   // [4096][512] bf16 (combined)
    const ushort* __restrict__ B,   // [32000][512] bf16 (Wout)
    float* __restrict__ Out) {      // [4096][32000] f32
  constexpr int K = 512, NTT = 16, LDC = 32000;
  __shared__ ushort As[2][128 * 32], Bs[2][128 * 32];  // 32 KiB

  int wg = blockIdx.x;                          // 8000 blocks, 8000 % 8 == 0
  int swz = (wg & 7) * 1000 + (wg >> 3);
  const int colT = swz / 32, rowT = swz % 32;   // 32 row-tiles share each B col-panel
  const int row0 = rowT * 128, col0 = colT * 128;

  const int tid = threadIdx.x, wid = tid >> 6, lane = tid & 63;
  const int wr = wid >> 1, wc = wid & 1;        // wave tile: 64 rows x 64 cols
  const int l15 = lane & 15;
  const int kslot = lane >> 4;

  const ushort* Ab = A + (long)row0 * K;
  const ushort* Bb = B + (long)col0 * K;
  f32x4 acc[4][4] = {};

  stage32<2>(Ab, K, As[0], wid, lane);
  stage32<2>(Bb, K, Bs[0], wid, lane);

  for (int t = 0; t < NTT; t++) {
    if (t + 1 < NTT) {
      stage32<2>(Ab + (t + 1) * 32, K, As[(t + 1) & 1], wid, lane);
      stage32<2>(Bb + (t + 1) * 32, K, Bs[(t + 1) & 1], wid, lane);
      asm volatile("s_waitcnt vmcnt(4)" ::: "memory");
    } else {
      asm volatile("s_waitcnt vmcnt(0)" ::: "memory");
    }
    __builtin_amdgcn_s_barrier();
    __builtin_amdgcn_sched_barrier(0);
    const ushort* as = As[t & 1];
    const ushort* bs = Bs[t & 1];
    bf16x8 av[4], bv[4];
#pragma unroll
    for (int i = 0; i < 4; i++) av[i] = frag_read32(as, wr * 64 + i * 16 + l15, kslot);
#pragma unroll
    for (int j = 0; j < 4; j++) bv[j] = frag_read32(bs, wc * 64 + j * 16 + l15, kslot);
    __builtin_amdgcn_s_setprio(1);
#pragma unroll
    for (int i = 0; i < 4; i++)
#pragma unroll
      for (int j = 0; j < 4; j++)
        acc[i][j] = MFMA16(av[i], bv[j], acc[i][j]);
    __builtin_amdgcn_s_setprio(0);
    asm volatile("s_waitcnt lgkmcnt(0)" ::: "memory");
    __builtin_amdgcn_sched_barrier(0);
    __builtin_amdgcn_s_barrier();
  }

  // nt stores: 64B contiguous sectors, no L2 allocation (keeps A/B panels resident).
#pragma unroll
  for (int i = 0; i < 4; i++) {
    int r = row0 + wr * 64 + i * 16 + ((lane >> 4) * 4);
#pragma unroll
    for (int j = 0; j < 4; j++) {
      int c = col0 + wc * 64 + j * 16 + l15;
#pragma unroll
      for (int q = 0; q < 4; q++)
        __builtin_nontemporal_store(acc[i][j][q], &Out[(long)(r + q) * LDC + c]);
    }
  }
}

extern "C" void kernel_launch(void* const* d_in, const int* in_sizes, int n_in,
                              void* d_out, int out_size, void* d_ws, size_t ws_size,
                              hipStream_t stream) {
  const float* hidden = (const float*)d_in[0];   // [8,512,512]
  const float* eprobs = (const float*)d_in[1];   // [8,16]
  const float* Wg     = (const float*)d_in[2];   // [16,2048,512]
  const float* Wu     = (const float*)d_in[3];   // [16,2048,512]
  const float* Wd     = (const float*)d_in[4];   // [16,512,2048]
  const float* Wout   = (const float*)d_in[5];   // [32000,512]
  float* out = (float*)d_out;                    // [8,512,32000] f32

  char* ws = (char*)d_ws;
  ushort* h_bf  = (ushort*)(ws + 256);         // 8*512*512
  ushort* wo_bf = h_bf  + 2097152L;            // 32000*512
  ushort* Gbuf  = wo_bf + 16384000L;           // 16*512*2048 bf16
  ushort* Cb    = Gbuf  + 16777216L;           // 8*512*512 bf16

  hipLaunchKernelGGL(cvt_hw, dim3(2048), dim3(256), 0, stream, hidden, Wout, h_bf, wo_bf);
  // gate/up: Wg/Wu consumed as f32 (conversion fused into staging)
  hipLaunchKernelGGL(gateup128, dim3(2048), dim3(256), 0, stream,
                     h_bf, Wg, Wu, eprobs, Gbuf);
  // down + combine: Wd consumed as f32
  hipLaunchKernelGGL(down_fused, dim3(4, 16, 8), dim3(256), 0, stream,
                     Gbuf, Wd, eprobs, Cb);
  // output projection: 128x128 tiles BK=32, 8000 blocks, 4 blocks/CU, nt stores
  hipLaunchKernelGGL(gemm128_final, dim3(8000), dim3(256), 0, stream, Cb, wo_bf, out);
}